// Round 7
// baseline (131.615 us; speedup 1.0000x reference)
//
#include <hip/hip_runtime.h>
#include <math.h>

#define HH 1024
#define WW 1024
#define OUTW 58            // output columns per wave (64 lanes - 6 halo)
#define RPB 4              // output rows per WAVE (vertical slide length)
#define WPB 8              // waves per block (independent y-strips, no barrier)
#define OFF(i) ((i)*8 - (i)*((i)-1)/2)   // packed upper-tri row offset

// ===== R23: WPB 4->8 — attack the ~1.3-blocks/CU concurrency limit =====
// Hard-won constraints (rounds 4..22):
//  - VGPR bucket MUST stay 128. WRITE_SIZE == 13536 KB is the no-spill
//    invariant (violations: r7/r16/r17/r18).
//  - R19 DPP htap: VGPR 128->76. R20 depth-1 prefetch: 53.5 us (champ).
//    R21 depth-2 + SGPR bases: 96 VGPR, FETCH 85->67 MB, dur 53.7.
//    R22 RPB=8: REGRESSED 58.5 (tau 16->29 us, concurrency ~1.1).
//  - Model fit (R19..R22): concurrent blocks/CU ~= 1.1-1.9 regardless of
//    VGPR/grid; dur ~ (blocks/CU x tau) / concurrency. The residency
//    limit is BLOCK-granular, not wave-granular.
//  - Cross-lane ops (DPP) never inside divergent flow (r8).
//  - No LDS prefetch: s_waitcnt vmcnt(0) drains output stores (r15).
// R23 change vs R21 (body verbatim): WPB=8 (512-thr blocks, 0 LDS, no
//  barriers). Same 4608 waves, same tau; ~1.3 blocks/CU now carries ~10
//  waves/CU instead of ~5.3. (r13 "TLP up regressed" was on the old
//  128-VGPR bpermute kernel - register file couldn't hold the waves.)

// DPP move, bound_ctrl=1 (invalid lanes read 0)
template<int CTRL>
__device__ __forceinline__ float dpp0(float x) {
    return __int_as_float(
        __builtin_amdgcn_update_dpp(0, __float_as_int(x), CTRL, 0xf, 0xf, true));
}
// whole-wave shift right by 1 lane (crosses 16-lane row boundaries)
__device__ __forceinline__ float wshr1(float x) { return dpp0<0x138>(x); }

// fp32 reciprocal: v_rcp_f32 + 1 Newton step (~1ulp); LDL^T is sqrt-free
__device__ __forceinline__ float frcp_fast(float s) {
    float r = __builtin_amdgcn_rcpf(s);
    return r * fmaf(-s, r, 2.0f);
}

static_assert(RPB == 4, "iteration schedule below is hand-unrolled for RPB=4");

__global__ __launch_bounds__(WPB * 64, 2) void ls_sep_kernel(
    const float* __restrict__ inp,    // [3,H,W]
    const float* __restrict__ dep,    // [1,H,W]
    const float* __restrict__ alb,    // [3,H,W]
    const float* __restrict__ nrm,    // [3,H,W]
    float* __restrict__ out)          // [3,H,W]
{
    const int L  = threadIdx.x & 63;          // lane 0..63
    const int wv = threadIdx.x >> 6;          // wave 0..7 (independent y-strip)
    const int HW = HH * WW;
    // lane L sums column x; its horizontal window (x-6..x) is centered at x-3
    const int x  = OUTW * blockIdx.x - 3 + L;
    const int y0 = (RPB * WPB) * blockIdx.y + RPB * wv;
    const int px = x - 3;                     // output pixel column for this lane

    const int xc    = min(max(x, 0), WW - 1);
    const float xok = (x >= 0 && x < WW) ? 1.f : 0.f;

    // per-channel SGPR base pointers (one s-pair each; loads share voffset)
    const float* __restrict__ d0 = dep;
    const float* __restrict__ a0 = alb;
    const float* __restrict__ a1 = alb + HW;
    const float* __restrict__ a2 = alb + 2 * HW;
    const float* __restrict__ n0 = nrm;
    const float* __restrict__ n1 = nrm + HW;
    const float* __restrict__ n2 = nrm + 2 * HW;
    const float* __restrict__ i0 = inp;
    const float* __restrict__ i1 = inp + HW;
    const float* __restrict__ i2 = inp + 2 * HW;
    float* __restrict__ o0 = out;
    float* __restrict__ o1 = out + HW;
    float* __restrict__ o2 = out + 2 * HW;

    float C[60];                              // running column sums (7 rows in y)
    #pragma unroll
    for (int k = 0; k < 60; k++) C[k] = 0.f;

    // clamped-address loads only; no C update (prefetchable)
    auto load_row = [&](int yy, float (&fv)[8], float (&yv)[3]) {
        const int yc = min(max(yy, 0), HH - 1);
        const int p = yc * WW + xc;
        fv[0] = 1.f;
        fv[1] = d0[p];
        fv[2] = a0[p];
        fv[3] = a1[p];
        fv[4] = a2[p];
        fv[5] = n0[p];
        fv[6] = n1[p];
        fv[7] = n2[p];
        yv[0] = i0[p];
        yv[1] = i1[p];
        yv[2] = i2[p];
    };

    // masked accumulate of a loaded row into the column sums
    auto apply_row = [&](const float (&fv)[8], const float (&yv)[3],
                         int yy, float sgn) {
        const float ok = (yy >= 0 && yy < HH) ? xok : 0.f;
        const float s = sgn * ok;
        float fs[8];
        #pragma unroll
        for (int i = 0; i < 8; i++) fs[i] = fv[i] * s;
        int k = 0;
        #pragma unroll
        for (int i = 0; i < 8; i++)
            #pragma unroll
            for (int j = i; j < 8; j++) { C[k] = fmaf(fs[i], fv[j], C[k]); k++; }
        #pragma unroll
        for (int i = 0; i < 8; i++)
            #pragma unroll
            for (int c = 0; c < 3; c++)
                C[36 + i * 3 + c] = fmaf(fs[i], yv[c], C[36 + i * 3 + c]);
    };

    // prologue: fill the depth-2 add-row pipeline
    float A0f[8], A0y[3], A1f[8], A1y[3];
    load_row(y0 + 3, A0f, A0y);
    load_row(y0 + 4, A1f, A1y);

    // preload rows y0-3 .. y0+2 (iter y0 skips the subtract)
    #pragma unroll 2
    for (int yy = y0 - 3; yy < y0 + 3; yy++) {
        float fv[8], yv[3];
        load_row(yy, fv, yv);
        apply_row(fv, yv, yy, 1.f);
    }

    float Sf[8], Sy[3];                       // sub-row buffer (depth 1)

    const int pxc = min(max(px, 0), WW - 1);
    const bool do_store = (L >= 6) && (px < WW);

    // Batched horizontal 7-tap over lanes L-6..L for 12 values at once.
    // 6-step fused-DPP prefix chain (v_add_f32_dpp, no DS ops).
    // MUST be called by all 64 lanes (cross-lane inside).
    auto htap12 = [&](int base, float* dst) {
        #pragma unroll
        for (int j = 0; j < 12; j++) {
            const float xv = C[base + j];
            float S = xv;
            #pragma unroll
            for (int t = 0; t < 6; t++) S = xv + wshr1(S);
            dst[j] = S;
        }
    };

    // one output row; Af/Ay is the add-row buffer holding row y+3.
    // loadA: refill Af with row y+5 (consumed 2 iters later).
    // loadS: refill Sf with row y-3 (consumed next iter).
    auto iter = [&](int y, float (&Af)[8], float (&Ay)[3],
                    bool first, bool loadA, bool loadS) {
        // ---- consume prefetched rows ----
        apply_row(Af, Ay, y + 3, 1.f);
        if (!first) apply_row(Sf, Sy, y - 4, -1.f);

        // ---- issue loads in consumption order: cf -> S -> A ----
        const int pc = y * WW + pxc;          // center features (this iter)
        float cf[8];
        cf[0] = 1.f;
        cf[1] = d0[pc];
        cf[2] = a0[pc]; cf[3] = a1[pc]; cf[4] = a2[pc];
        cf[5] = n0[pc]; cf[6] = n1[pc]; cf[7] = n2[pc];

        if (loadS) load_row(y - 3, Sf, Sy);   // next iter's sub-row
        if (loadA) load_row(y + 5, Af, Ay);   // iter+2's add-row

        // ---- horizontal taps for AtA (AtY deferred past the solve) ----
        float W[36];
        htap12(0,  &W[0]);
        htap12(12, &W[12]);
        htap12(24, &W[24]);
        #pragma unroll
        for (int i = 0; i < 8; i++) W[OFF(i)] += 1.0e-4f;

        // ---- fp32 LDL^T (sqrt-free). W row i keeps R_ij = d_i*U_ij ----
        float idv[8];
        #pragma unroll
        for (int i = 0; i < 8; i++) {
            #pragma unroll
            for (int k = 0; k < i; k++) {
                const float c = W[OFF(k) + i - k] * idv[k];   // U_ki
                #pragma unroll
                for (int j = i; j < 8; j++)
                    W[OFF(i) + j - i] = fmaf(-c, W[OFF(k) + j - k], W[OFF(i) + j - i]);
            }
            idv[i] = frcp_fast(W[OFF(i)]);    // 1/d_i
        }

        // forward: vt_i = idv_i * (cf_i - sum_{k<i} R_ki * vt_k)
        float vt[8];
        #pragma unroll
        for (int i = 0; i < 8; i++) {
            float s = cf[i];
            #pragma unroll
            for (int k = 0; k < i; k++)
                s = fmaf(-W[OFF(k) + i - k], vt[k], s);
            vt[i] = s * idv[i];
        }
        // back: w_i = vt_i - idv_i * sum_{j>i} R_ij * w_j
        float w[8];
        #pragma unroll
        for (int i = 7; i >= 0; i--) {
            float t = 0.f;
            #pragma unroll
            for (int j = i + 1; j < 8; j++)
                t = fmaf(W[OFF(i) + j - i], w[j], t);
            w[i] = fmaf(-idv[i], t, vt[i]);
        }

        // ---- deferred AtY taps (batched) + output dot products:
        //      ALL lanes execute; only the store is predicated ----
        float r[3] = {0.f, 0.f, 0.f};
        {
            float SY[12];
            htap12(36, SY);                   // AtY for i=0..3
            #pragma unroll
            for (int i = 0; i < 4; i++)
                #pragma unroll
                for (int c = 0; c < 3; c++)
                    r[c] = fmaf(w[i], SY[i * 3 + c], r[c]);
            htap12(48, SY);                   // AtY for i=4..7
            #pragma unroll
            for (int i = 0; i < 4; i++)
                #pragma unroll
                for (int c = 0; c < 3; c++)
                    r[c] = fmaf(w[i + 4], SY[i * 3 + c], r[c]);
        }

        if (do_store) {
            const int p = y * WW + px;
            o0[p] = r[0];
            o1[p] = r[1];
            o2[p] = r[2];
        }
    };

    // hand-unrolled schedule (RPB=4): minimal loads, static buffers
    iter(y0,     A0f, A0y, true,  true,  true);   // A0<-y0+5, S<-y0-3
    iter(y0 + 1, A1f, A1y, false, true,  true);   // A1<-y0+6, S<-y0-2
    iter(y0 + 2, A0f, A0y, false, false, true);   // consume y0+5, S<-y0-1
    iter(y0 + 3, A1f, A1y, false, false, false);  // consume y0+6
}

extern "C" void kernel_launch(void* const* d_in, const int* in_sizes, int n_in,
                              void* d_out, int out_size, void* d_ws, size_t ws_size,
                              hipStream_t stream) {
    const float* inp = (const float*)d_in[0];
    const float* dep = (const float*)d_in[1];
    const float* alb = (const float*)d_in[2];
    const float* nrm = (const float*)d_in[3];
    float* out = (float*)d_out;
    dim3 grid((WW + OUTW - 1) / OUTW, HH / (RPB * WPB));   // 18 x 32, 512-thr blocks
    ls_sep_kernel<<<grid, dim3(WPB * 64), 0, stream>>>(inp, dep, alb, nrm, out);
}

// Round 8
// 125.471 us; speedup vs baseline: 1.0490x; 1.0490x over previous
//
#include <hip/hip_runtime.h>
#include <math.h>

#define HH 1024
#define WW 1024
#define OUTW 58            // output columns per wave (64 lanes - 6 halo)
#define RPB 4              // output rows per WAVE (vertical slide length)
#define WPB 4              // waves per block (independent y-strips, no barrier)
#define OFF(i) ((i)*8 - (i)*((i)-1)/2)   // packed upper-tri row offset

// ===== R24: pipeline next-iter row-applies INTO the solve's bubbles =====
// Hard-won constraints (rounds 4..23):
//  - VGPR bucket MUST stay 128. WRITE_SIZE == 13536 KB is the no-spill
//    invariant (violations: r7/r16/r17/r18).
//  - R19 DPP htap: VGPR 128->76. R20 depth-1 prefetch: 53.5 us (champ).
//    R21 depth-2 + SGPR bases: 96 VGPR, dur 53.7. R22 RPB=8: 58.5.
//    R23 WPB=8: 61.9 (better L2, worse dur) -> block-concurrency theory
//    refuted.
//  - Accounting invariant: VALUBusy x dur ~= 25-26 us (total VALU work);
//    VALUBusy stuck 42-50% across occupancy 4.4-7.7 waves/CU -> NOT
//    TLP-limited, NOT VMEM-limited. Remaining hole: per-wave ILP in the
//    LDL^T solve (~300-400 cy of serial FMA + 8 serial rcp per iter).
//  - Cross-lane ops (DPP) never inside divergent flow (r8).
//  - No LDS prefetch: s_waitcnt vmcnt(0) drains output stores (r15).
// R24 change vs R21: split apply_row into applyA (C[0..35]) / applyY
//  (C[36..59]); execute NEXT iteration's add/sub applies one iter early -
//  applyA pair (88 indep FMAs) in the solve region (after AtA taps, which
//  anti-dependence-order against C writes), applyY pair after AtY taps +
//  dots. Next iter starts with no top applies. Same rows, same order,
//  same arithmetic (one benign re-association in applyY's mask fold).

// DPP move, bound_ctrl=1 (invalid lanes read 0)
template<int CTRL>
__device__ __forceinline__ float dpp0(float x) {
    return __int_as_float(
        __builtin_amdgcn_update_dpp(0, __float_as_int(x), CTRL, 0xf, 0xf, true));
}
// whole-wave shift right by 1 lane (crosses 16-lane row boundaries)
__device__ __forceinline__ float wshr1(float x) { return dpp0<0x138>(x); }

// fp32 reciprocal: v_rcp_f32 + 1 Newton step (~1ulp); LDL^T is sqrt-free
__device__ __forceinline__ float frcp_fast(float s) {
    float r = __builtin_amdgcn_rcpf(s);
    return r * fmaf(-s, r, 2.0f);
}

static_assert(RPB == 4, "iteration schedule below is hand-unrolled for RPB=4");

__global__ __launch_bounds__(WPB * 64, 2) void ls_sep_kernel(
    const float* __restrict__ inp,    // [3,H,W]
    const float* __restrict__ dep,    // [1,H,W]
    const float* __restrict__ alb,    // [3,H,W]
    const float* __restrict__ nrm,    // [3,H,W]
    float* __restrict__ out)          // [3,H,W]
{
    const int L  = threadIdx.x & 63;          // lane 0..63
    const int wv = threadIdx.x >> 6;          // wave 0..3 (independent y-strip)
    const int HW = HH * WW;
    // lane L sums column x; its horizontal window (x-6..x) is centered at x-3
    const int x  = OUTW * blockIdx.x - 3 + L;
    const int y0 = (RPB * WPB) * blockIdx.y + RPB * wv;
    const int px = x - 3;                     // output pixel column for this lane

    const int xc    = min(max(x, 0), WW - 1);
    const float xok = (x >= 0 && x < WW) ? 1.f : 0.f;

    // per-channel SGPR base pointers (one s-pair each; loads share voffset)
    const float* __restrict__ d0 = dep;
    const float* __restrict__ a0 = alb;
    const float* __restrict__ a1 = alb + HW;
    const float* __restrict__ a2 = alb + 2 * HW;
    const float* __restrict__ n0 = nrm;
    const float* __restrict__ n1 = nrm + HW;
    const float* __restrict__ n2 = nrm + 2 * HW;
    const float* __restrict__ i0 = inp;
    const float* __restrict__ i1 = inp + HW;
    const float* __restrict__ i2 = inp + 2 * HW;
    float* __restrict__ o0 = out;
    float* __restrict__ o1 = out + HW;
    float* __restrict__ o2 = out + 2 * HW;

    float C[60];                              // running column sums (7 rows in y)
    #pragma unroll
    for (int k = 0; k < 60; k++) C[k] = 0.f;

    // clamped-address loads only; no C update (prefetchable)
    auto load_row = [&](int yy, float (&fv)[8], float (&yv)[3]) {
        const int yc = min(max(yy, 0), HH - 1);
        const int p = yc * WW + xc;
        fv[0] = 1.f;
        fv[1] = d0[p];
        fv[2] = a0[p];
        fv[3] = a1[p];
        fv[4] = a2[p];
        fv[5] = n0[p];
        fv[6] = n1[p];
        fv[7] = n2[p];
        yv[0] = i0[p];
        yv[1] = i1[p];
        yv[2] = i2[p];
    };

    // AtA half: 8 mul + 36 fma into C[0..35]
    auto applyA = [&](const float (&fv)[8], int yy, float sgn) {
        const float ok = (yy >= 0 && yy < HH) ? xok : 0.f;
        const float s = sgn * ok;
        float fs[8];
        #pragma unroll
        for (int i = 0; i < 8; i++) fs[i] = fv[i] * s;
        int k = 0;
        #pragma unroll
        for (int i = 0; i < 8; i++)
            #pragma unroll
            for (int j = i; j < 8; j++) { C[k] = fmaf(fs[i], fv[j], C[k]); k++; }
    };

    // AtY half: 3 mul + 24 fma into C[36..59] (mask folded into yv)
    auto applyY = [&](const float (&fv)[8], const float (&yv)[3],
                      int yy, float sgn) {
        const float ok = (yy >= 0 && yy < HH) ? xok : 0.f;
        const float s = sgn * ok;
        float sy[3];
        #pragma unroll
        for (int c = 0; c < 3; c++) sy[c] = yv[c] * s;
        #pragma unroll
        for (int i = 0; i < 8; i++)
            #pragma unroll
            for (int c = 0; c < 3; c++)
                C[36 + i * 3 + c] = fmaf(fv[i], sy[c], C[36 + i * 3 + c]);
    };

    // prologue: fill the add-row pipeline (Aa = y0+3 own-add, Ab = y0+4)
    float Aaf[8], Aay[3], Abf[8], Aby[3];
    load_row(y0 + 3, Aaf, Aay);
    load_row(y0 + 4, Abf, Aby);

    // preload rows y0-3 .. y0+2 (iter y0 skips the subtract)
    #pragma unroll 2
    for (int yy = y0 - 3; yy < y0 + 3; yy++) {
        float fv[8], yv[3];
        load_row(yy, fv, yv);
        applyA(fv, yy, 1.f);
        applyY(fv, yv, yy, 1.f);
    }

    float Sf[8], Sy[3];                       // sub-row buffer (depth 1)

    const int pxc = min(max(px, 0), WW - 1);
    const bool do_store = (L >= 6) && (px < WW);

    // Batched horizontal 7-tap over lanes L-6..L for 12 values at once.
    // 6-step fused-DPP prefix chain (v_add_f32_dpp, no DS ops).
    // MUST be called by all 64 lanes (cross-lane inside).
    auto htap12 = [&](int base, float* dst) {
        #pragma unroll
        for (int j = 0; j < 12; j++) {
            const float xv = C[base + j];
            float S = xv;
            #pragma unroll
            for (int t = 0; t < 6; t++) S = xv + wshr1(S);
            dst[j] = S;
        }
    };

    // one output row.
    //  Atf/Aty : own add row y+3 (applied at top, FIRST iter only)
    //  Anf/Any : next iter's add row y+4 (applied in solve / post-dots)
    //  Alf/Aly : load destination for row y+5
    auto iter = [&](int y,
                    float (&Atf)[8], float (&Aty)[3],
                    float (&Anf)[8], float (&Any)[3],
                    float (&Alf)[8], float (&Aly)[3],
                    bool first, bool loadA, bool nxt) {
        if (first) {                          // own add (window top row)
            applyA(Atf, y + 3, 1.f);
            applyY(Atf, Aty, y + 3, 1.f);
        }

        // ---- loads in consumption order: S (solve region), cf (fwd-sub),
        //      A (next iter's solve region) ----
        if (nxt) load_row(y - 3, Sf, Sy);     // next window's sub-row

        const int pc = y * WW + pxc;          // center features (this iter)
        float cf[8];
        cf[0] = 1.f;
        cf[1] = d0[pc];
        cf[2] = a0[pc]; cf[3] = a1[pc]; cf[4] = a2[pc];
        cf[5] = n0[pc]; cf[6] = n1[pc]; cf[7] = n2[pc];

        if (loadA) load_row(y + 5, Alf, Aly); // add-row two windows ahead

        // ---- horizontal taps for AtA ----
        float W[36];
        htap12(0,  &W[0]);
        htap12(12, &W[12]);
        htap12(24, &W[24]);
        #pragma unroll
        for (int i = 0; i < 8; i++) W[OFF(i)] += 1.0e-4f;

        // ---- pipelined AtA applies for NEXT iter: 88 independent FMAs
        //      to fill the LDL^T's serial-latency bubbles (C[0..35] was
        //      fully consumed by the taps above; anti-dep keeps order) ----
        if (nxt) {
            applyA(Anf, y + 4, 1.f);
            applyA(Sf, y - 3, -1.f);
        }

        // ---- fp32 LDL^T (sqrt-free). W row i keeps R_ij = d_i*U_ij ----
        float idv[8];
        #pragma unroll
        for (int i = 0; i < 8; i++) {
            #pragma unroll
            for (int k = 0; k < i; k++) {
                const float c = W[OFF(k) + i - k] * idv[k];   // U_ki
                #pragma unroll
                for (int j = i; j < 8; j++)
                    W[OFF(i) + j - i] = fmaf(-c, W[OFF(k) + j - k], W[OFF(i) + j - i]);
            }
            idv[i] = frcp_fast(W[OFF(i)]);    // 1/d_i
        }

        // forward: vt_i = idv_i * (cf_i - sum_{k<i} R_ki * vt_k)
        float vt[8];
        #pragma unroll
        for (int i = 0; i < 8; i++) {
            float s = cf[i];
            #pragma unroll
            for (int k = 0; k < i; k++)
                s = fmaf(-W[OFF(k) + i - k], vt[k], s);
            vt[i] = s * idv[i];
        }
        // back: w_i = vt_i - idv_i * sum_{j>i} R_ij * w_j
        float w[8];
        #pragma unroll
        for (int i = 7; i >= 0; i--) {
            float t = 0.f;
            #pragma unroll
            for (int j = i + 1; j < 8; j++)
                t = fmaf(W[OFF(i) + j - i], w[j], t);
            w[i] = fmaf(-idv[i], t, vt[i]);
        }

        // ---- AtY taps (batched) + output dot products ----
        float r[3] = {0.f, 0.f, 0.f};
        {
            float SY[12];
            htap12(36, SY);                   // AtY for i=0..3
            #pragma unroll
            for (int i = 0; i < 4; i++)
                #pragma unroll
                for (int c = 0; c < 3; c++)
                    r[c] = fmaf(w[i], SY[i * 3 + c], r[c]);
            htap12(48, SY);                   // AtY for i=4..7
            #pragma unroll
            for (int i = 0; i < 4; i++)
                #pragma unroll
                for (int c = 0; c < 3; c++)
                    r[c] = fmaf(w[i + 4], SY[i * 3 + c], r[c]);
        }

        // ---- pipelined AtY applies for NEXT iter (C[36..59] consumed) ----
        if (nxt) {
            applyY(Anf, Any, y + 4, 1.f);
            applyY(Sf, Sy, y - 3, -1.f);
        }

        if (do_store) {
            const int p = y * WW + px;
            o0[p] = r[0];
            o1[p] = r[1];
            o2[p] = r[2];
        }
    };

    // hand-unrolled schedule (RPB=4), Aa/Ab ping-pong:
    //  y0  : own-add Aa(y0+3); next-add Ab(y0+4); load Aa<-y0+5; S<-y0-3
    //  y0+1: next-add Aa(y0+5); load Ab<-y0+6; S<-y0-2
    //  y0+2: next-add Ab(y0+6); S<-y0-1
    //  y0+3: compute+store only
    iter(y0,     Aaf, Aay, Abf, Aby, Aaf, Aay, true,  true,  true);
    iter(y0 + 1, Aaf, Aay, Aaf, Aay, Abf, Aby, false, true,  true);
    iter(y0 + 2, Aaf, Aay, Abf, Aby, Aaf, Aay, false, false, true);
    iter(y0 + 3, Aaf, Aay, Aaf, Aay, Abf, Aby, false, false, false);
}

extern "C" void kernel_launch(void* const* d_in, const int* in_sizes, int n_in,
                              void* d_out, int out_size, void* d_ws, size_t ws_size,
                              hipStream_t stream) {
    const float* inp = (const float*)d_in[0];
    const float* dep = (const float*)d_in[1];
    const float* alb = (const float*)d_in[2];
    const float* nrm = (const float*)d_in[3];
    float* out = (float*)d_out;
    dim3 grid((WW + OUTW - 1) / OUTW, HH / (RPB * WPB));   // 18 x 64, 256-thr blocks
    ls_sep_kernel<<<grid, dim3(WPB * 64), 0, stream>>>(inp, dep, alb, nrm, out);
}